// Round 4
// baseline (871.197 us; speedup 1.0000x reference)
//
#include <hip/hip_runtime.h>

#define VOCAB 12288
#define EMB 128
#define NBLK ((VOCAB / 128) * (VOCAB / 128))   // 9216 output tiles

typedef unsigned short u16;
typedef __bf16 bf16x8 __attribute__((ext_vector_type(8)));
typedef float f32x4 __attribute__((ext_vector_type(4)));

#define AS1 __attribute__((address_space(1)))
#define AS3 __attribute__((address_space(3)))

__device__ __forceinline__ u16 f2bf(float f) {
    unsigned u = __float_as_uint(f);
    u += 0x7FFF + ((u >> 16) & 1);   // round-to-nearest-even
    return (u16)(u >> 16);
}

__device__ __forceinline__ void load_lds16(const void* g, void* l) {
    __builtin_amdgcn_global_load_lds((AS1 void*)const_cast<void*>(g),
                                     (AS3 void*)l, 16, 0, 0);
}

// hw transcendentals: v_exp_f32 = 2^x, v_log_f32 = log2(x)
__device__ __forceinline__ float hw_exp2(float x) { return __builtin_amdgcn_exp2f(x); }
__device__ __forceinline__ float hw_log2(float x) { return __builtin_amdgcn_logf(x); }

// Kernel 1: zero the output scalar + cast both embedding matrices fp32->bf16 into ws.
__global__ __launch_bounds__(256) void glove_prep(
        const float* __restrict__ tgt, const float* __restrict__ ctx,
        u16* __restrict__ tgtb, u16* __restrict__ ctxb, float* __restrict__ out) {
    int idx = blockIdx.x * 256 + threadIdx.x;
    if (idx == 0) out[0] = 0.0f;
    const int N4 = (VOCAB * EMB) / 4;   // 393216 float4s per matrix
    const float4* __restrict__ s;
    u16* __restrict__ d;
    int k = idx;
    if (k < N4) { s = (const float4*)tgt; d = tgtb; }
    else        { k -= N4; s = (const float4*)ctx; d = ctxb; }
    float4 v = s[k];
    unsigned lo = (unsigned)f2bf(v.x) | ((unsigned)f2bf(v.y) << 16);
    unsigned hi = (unsigned)f2bf(v.z) | ((unsigned)f2bf(v.w) << 16);
    ((uint2*)d)[k] = make_uint2(lo, hi);
}

// Kernel 2: fused dots-MFMA + weighted-squared-diff reduction.
// 128x128 output tile / block. NEW this round: the X tile (64 KB) is staged
// into LDS via global_load_lds (1-KB contiguous bursts, 16 in flight/wave),
// issued BEFORE the MFMA phase and waited with counted vmcnt + raw s_barrier
// so the HBM stream overlaps compute. Theory: the old per-thread scalar
// nontemporal X loads (64B segments, 48KB row stride, nt-bypassed caches)
// were the 4x-over-roofline bottleneck (1.6 TB/s effective).
// LDS = 32+32+64 = 128 KB -> 1 block/CU; X fetch is DMA-deep so TLP loss ok.
__global__ __launch_bounds__(256) void glove_main(
        const float* __restrict__ X,
        const u16* __restrict__ ctxb, const u16* __restrict__ tgtb,
        const float* __restrict__ tb, const float* __restrict__ cb,
        float* __restrict__ out, float* __restrict__ partial) {
    __shared__ __bf16 smA[128 * EMB];   // context tile (rows i), xor-swizzled chunks
    __shared__ __bf16 smB[128 * EMB];   // target tile  (rows j), xor-swizzled chunks
    __shared__ float  smX[128 * 128];   // X tile, 16B-chunk xor-swizzled (see below)

    const int tid  = threadIdx.x;
    const int lane = tid & 63;
    const int wave = tid >> 6;
    const int quad = lane >> 4;
    const int ln   = lane & 15;

    // XCD-slab swizzle: blocks bid%8 -> XCD (heuristic). Each XCD works a slab of
    // 12 ctx-tile rows so its ctx tiles (384KB) + streamed tgt tiles stay L2-hot.
    int bid = blockIdx.x;                 // 0..9215
    int xcd = bid & 7;
    int idx = bid >> 3;                   // 0..1151
    int by  = xcd * 12 + (idx / 96);      // ctx tile row 0..95
    int bx  = idx % 96;                   // tgt tile col 0..95

    const int bi = by * 128;              // context row base (i)
    const int bj = bx * 128;              // target row base  (j)

    // Tiles are 128 consecutive rows x full K=128 -> contiguous 32KB in memory.
    const u16* gA = ctxb + (size_t)bi * EMB;
    const u16* gB = tgtb + (size_t)bj * EMB;

    // --- Stage A,B (16 instrs/wave) via global_load_lds width=16. LDS chunk
    // L=(row,cp) holds global chunk (row, cp ^ (row&15)) -> conflict-free
    // ds_read_b128 frag reads. These go to L2-hot embedding copies.
#pragma unroll
    for (int p = 0; p < 8; ++p) {
        int base = p * 256 + wave * 64;   // wave-uniform chunk base
        int L    = base + lane;
        int row  = L >> 4;
        int c    = (L & 15) ^ (row & 15);
        load_lds16(gA + row * EMB + c * 8, smA + base * 8);
        load_lds16(gB + row * EMB + c * 8, smB + base * 8);
    }

    // --- Stage the full 128x128 f32 X tile (16 instrs/wave, 1KB each).
    // Linear LDS dest (load_lds constraint) + pre-swizzled SOURCE column chunk:
    // LDS 16B-chunk (row, c16) holds global chunk (row, c16 ^ ((row&12)>>1)),
    // giving free 2-way bank aliasing on the quad-spread epilogue reads.
    const float* gX = X + (size_t)bi * VOCAB + bj;
#pragma unroll
    for (int t = 0; t < 16; ++t) {
        int g   = wave * 16 + t;          // 1-KB chunk id, wave-uniform
        int row = 2 * g + (lane >> 5);    // tile row 0..127 (per-lane)
        int c16 = lane & 31;              // 16B chunk within row
        int cs  = c16 ^ ((row & 12) >> 1);
        load_lds16(gX + (size_t)row * VOCAB + cs * 4, smX + g * 256);
    }

    // Wait A/B only (16 newest = X still streaming), then barrier.
    asm volatile("s_waitcnt vmcnt(16)" ::: "memory");
    __builtin_amdgcn_s_barrier();

    const int m_off = (wave & 1) * 64;    // ctx sub-rows for this wave
    const int n_off = (wave >> 1) * 64;   // tgt sub-cols for this wave

    f32x4 acc[4][4];
#pragma unroll
    for (int m = 0; m < 4; ++m)
#pragma unroll
        for (int n = 0; n < 4; ++n)
            acc[m][n] = (f32x4){0.f, 0.f, 0.f, 0.f};

#pragma unroll
    for (int s = 0; s < 4; ++s) {         // K-steps of 32
        bf16x8 af[4], bf[4];
#pragma unroll
        for (int m = 0; m < 4; ++m) {
            int row = m_off + m * 16 + ln;             // A: m = lane&15
            int cp  = (s * 4 + quad) ^ (row & 15);     // k-chunk, unswizzle
            af[m] = *(const bf16x8*)(smA + row * EMB + cp * 8);
        }
#pragma unroll
        for (int n = 0; n < 4; ++n) {
            int row = n_off + n * 16 + ln;             // B: n = lane&15
            int cp  = (s * 4 + quad) ^ (row & 15);
            bf[n] = *(const bf16x8*)(smB + row * EMB + cp * 8);
        }
#pragma unroll
        for (int m = 0; m < 4; ++m)
#pragma unroll
            for (int n = 0; n < 4; ++n)
                acc[m][n] = __builtin_amdgcn_mfma_f32_16x16x32_bf16(
                                af[m], bf[n], acc[m][n], 0, 0, 0);
    }

    // Wait X fully landed, then barrier (raw: no lgkm drain needed, vm only).
    asm volatile("s_waitcnt vmcnt(0)" ::: "memory");
    __builtin_amdgcn_s_barrier();

    // Epilogue. C/D layout: col(j) = lane&15, row(i) = quad*4 + reg.
    const int gi0 = bi + m_off;
    const int gj0 = bj + n_off;

    float tbv[4];
#pragma unroll
    for (int n = 0; n < 4; ++n) tbv[n] = tb[gj0 + n * 16 + ln];

    const float LN2 = 0.69314718055994531f;
    float sum = 0.0f;
#pragma unroll
    for (int m = 0; m < 4; ++m) {
#pragma unroll
        for (int r = 0; r < 4; ++r) {
            int il = m_off + m * 16 + quad * 4 + r;    // tile-local X row
            float cbi = cb[bi + il];
            const float* xrow = smX + il * 128;
#pragma unroll
            for (int n = 0; n < 4; ++n) {
                int col  = (n_off + n * 16) + ln;      // tile-local X col
                int c16s = (col >> 2) ^ (quad << 1);   // unswizzle 16B chunk
                float x  = xrow[(c16s << 2) + (col & 3)];
                float d  = acc[m][n][r] + tbv[n] + cbi - LN2 * hw_log2(1.0f + x);
                float xs = x * 0.01f;
                float w  = hw_exp2(0.75f * hw_log2(xs));   // xs^0.75; xs=0 -> 0
                w = fminf(w, 1.0f);
                sum = fmaf(w * d, d, sum);
            }
        }
    }

    // wave reduce -> cross-wave via LDS -> one plain store per block
#pragma unroll
    for (int off = 32; off > 0; off >>= 1) sum += __shfl_down(sum, off);

    __syncthreads();                       // everyone done with smA before reuse
    float* red = (float*)smA;
    if (lane == 0) red[wave] = sum;
    __syncthreads();
    if (tid == 0) {
        float v = red[0] + red[1] + red[2] + red[3];
        if (partial) partial[blockIdx.x] = v;   // no same-line contention
        else         atomicAdd(out, v);         // fallback if ws too small
    }
}

// Kernel 3: reduce the 9216 per-block partials (36KB, L2-hot) into out[0].
__global__ __launch_bounds__(256) void glove_reduce(
        const float* __restrict__ partial, float* __restrict__ out) {
    int tid = threadIdx.x;
    float s = 0.0f;
    const float4* p4 = (const float4*)partial;
    for (int k = tid; k < NBLK / 4; k += 256) {
        float4 v = p4[k];
        s += v.x + v.y + v.z + v.w;
    }
#pragma unroll
    for (int off = 32; off > 0; off >>= 1) s += __shfl_down(s, off);
    __shared__ float red[4];
    if ((tid & 63) == 0) red[tid >> 6] = s;
    __syncthreads();
    if (tid == 0) out[0] = red[0] + red[1] + red[2] + red[3];
}

extern "C" void kernel_launch(void* const* d_in, const int* in_sizes, int n_in,
                              void* d_out, int out_size, void* d_ws, size_t ws_size,
                              hipStream_t stream) {
    const float* X   = (const float*)d_in[0];
    const float* tgt = (const float*)d_in[1];
    const float* ctx = (const float*)d_in[2];
    const float* tb  = (const float*)d_in[3];
    const float* cb  = (const float*)d_in[4];
    float* out = (float*)d_out;

    u16* tgtb = (u16*)d_ws;
    u16* ctxb = tgtb + (size_t)VOCAB * EMB;

    // partial-sum array right after the two bf16 matrices (offset 6291456 B, 16B-aligned)
    const size_t emb_bytes = (size_t)VOCAB * EMB * sizeof(u16) * 2;
    float* partial = nullptr;
    if (ws_size >= emb_bytes + (size_t)NBLK * sizeof(float))
        partial = (float*)((char*)d_ws + emb_bytes);

    glove_prep<<<dim3(2 * (VOCAB * EMB / 4) / 256), 256, 0, stream>>>(
        tgt, ctx, tgtb, ctxb, out);
    glove_main<<<dim3(NBLK), 256, 0, stream>>>(
        X, ctxb, tgtb, tb, cb, out, partial);
    if (partial)
        glove_reduce<<<dim3(1), 256, 0, stream>>>(partial, out);
}

// Round 5
// 809.713 us; speedup vs baseline: 1.0759x; 1.0759x over previous
//
#include <hip/hip_runtime.h>

#define VOCAB 12288
#define EMB 128
#define NBLK ((VOCAB / 128) * (VOCAB / 128))   // 9216 output tiles

typedef unsigned short u16;
typedef __bf16 bf16x8 __attribute__((ext_vector_type(8)));
typedef float f32x4 __attribute__((ext_vector_type(4)));

#define AS1 __attribute__((address_space(1)))
#define AS3 __attribute__((address_space(3)))

__device__ __forceinline__ u16 f2bf(float f) {
    unsigned u = __float_as_uint(f);
    u += 0x7FFF + ((u >> 16) & 1);   // round-to-nearest-even
    return (u16)(u >> 16);
}

__device__ __forceinline__ void load_lds16(const void* g, void* l) {
    __builtin_amdgcn_global_load_lds((AS1 void*)const_cast<void*>(g),
                                     (AS3 void*)l, 16, 0, 0);
}

// hw transcendentals: v_exp_f32 = 2^x, v_log_f32 = log2(x)
__device__ __forceinline__ float hw_exp2(float x) { return __builtin_amdgcn_exp2f(x); }
__device__ __forceinline__ float hw_log2(float x) { return __builtin_amdgcn_logf(x); }

// Kernel 1: zero the output scalar + cast both embedding matrices fp32->bf16 into ws.
__global__ __launch_bounds__(256) void glove_prep(
        const float* __restrict__ tgt, const float* __restrict__ ctx,
        u16* __restrict__ tgtb, u16* __restrict__ ctxb, float* __restrict__ out) {
    int idx = blockIdx.x * 256 + threadIdx.x;
    if (idx == 0) out[0] = 0.0f;
    const int N4 = (VOCAB * EMB) / 4;   // 393216 float4s per matrix
    const float4* __restrict__ s;
    u16* __restrict__ d;
    int k = idx;
    if (k < N4) { s = (const float4*)tgt; d = tgtb; }
    else        { k -= N4; s = (const float4*)ctx; d = ctxb; }
    float4 v = s[k];
    unsigned lo = (unsigned)f2bf(v.x) | ((unsigned)f2bf(v.y) << 16);
    unsigned hi = (unsigned)f2bf(v.z) | ((unsigned)f2bf(v.w) << 16);
    ((uint2*)d)[k] = make_uint2(lo, hi);
}

// Kernel 2: fused dots-MFMA + weighted-squared-diff reduction.
// 128x128 output tile / block. R5: A/B tiles and the X tile TIME-SHARE one
// 64 KB LDS buffer (A/B are dead after the MFMA phase). This keeps R4's
// deep coalesced DMA staging of X (16 x 1KB bursts in flight per wave)
// while restoring 2 blocks/CU (2 waves/SIMD): one block's X-DMA overlaps
// the other block's trans-heavy epilogue. R4's regression isolated the
// bottleneck to occupancy+serialization, not request granularity.
__global__ __launch_bounds__(256) void glove_main(
        const float* __restrict__ X,
        const u16* __restrict__ ctxb, const u16* __restrict__ tgtb,
        const float* __restrict__ tb, const float* __restrict__ cb,
        float* __restrict__ out, float* __restrict__ partial) {
    __shared__ __attribute__((aligned(16))) unsigned char ldsbuf[65536];
    __bf16* smA = (__bf16*)ldsbuf;          // context tile (32 KB), phase 1
    __bf16* smB = smA + 128 * EMB;          // target tile  (32 KB), phase 1
    float*  smX = (float*)ldsbuf;           // X tile (64 KB), phase 2 overlay

    const int tid  = threadIdx.x;
    const int lane = tid & 63;
    const int wave = tid >> 6;
    const int quad = lane >> 4;
    const int ln   = lane & 15;

    // XCD-slab swizzle: blocks bid%8 -> XCD (heuristic). Each XCD works a slab of
    // 12 ctx-tile rows so its ctx tiles (384KB) + streamed tgt tiles stay L2-hot.
    int bid = blockIdx.x;                 // 0..9215
    int xcd = bid & 7;
    int idx = bid >> 3;                   // 0..1151
    int by  = xcd * 12 + (idx / 96);      // ctx tile row 0..95
    int bx  = idx % 96;                   // tgt tile col 0..95

    const int bi = by * 128;              // context row base (i)
    const int bj = bx * 128;              // target row base  (j)

    // Tiles are 128 consecutive rows x full K=128 -> contiguous 32KB in memory.
    const u16* gA = ctxb + (size_t)bi * EMB;
    const u16* gB = tgtb + (size_t)bj * EMB;

    // --- Phase 1: stage A,B via global_load_lds width=16 (L2-hot). LDS chunk
    // L=(row,cp) holds global chunk (row, cp ^ (row&15)) -> conflict-free
    // ds_read_b128 frag reads.
#pragma unroll
    for (int p = 0; p < 8; ++p) {
        int base = p * 256 + wave * 64;   // wave-uniform chunk base
        int L    = base + lane;
        int row  = L >> 4;
        int c    = (L & 15) ^ (row & 15);
        load_lds16(gA + row * EMB + c * 8, smA + base * 8);
        load_lds16(gB + row * EMB + c * 8, smB + base * 8);
    }
    __syncthreads();

    const int m_off = (wave & 1) * 64;    // ctx sub-rows for this wave
    const int n_off = (wave >> 1) * 64;   // tgt sub-cols for this wave

    f32x4 acc[4][4];
#pragma unroll
    for (int m = 0; m < 4; ++m)
#pragma unroll
        for (int n = 0; n < 4; ++n)
            acc[m][n] = (f32x4){0.f, 0.f, 0.f, 0.f};

#pragma unroll
    for (int s = 0; s < 4; ++s) {         // K-steps of 32
        bf16x8 af[4], bf[4];
#pragma unroll
        for (int m = 0; m < 4; ++m) {
            int row = m_off + m * 16 + ln;             // A: m = lane&15
            int cp  = (s * 4 + quad) ^ (row & 15);     // k-chunk, unswizzle
            af[m] = *(const bf16x8*)(smA + row * EMB + cp * 8);
        }
#pragma unroll
        for (int n = 0; n < 4; ++n) {
            int row = n_off + n * 16 + ln;             // B: n = lane&15
            int cp  = (s * 4 + quad) ^ (row & 15);
            bf[n] = *(const bf16x8*)(smB + row * EMB + cp * 8);
        }
#pragma unroll
        for (int m = 0; m < 4; ++m)
#pragma unroll
            for (int n = 0; n < 4; ++n)
                acc[m][n] = __builtin_amdgcn_mfma_f32_16x16x32_bf16(
                                af[m], bf[n], acc[m][n], 0, 0, 0);
    }

    // All waves done reading A/B from LDS (each wave's ds_reads are drained
    // before its MFMAs consumed them) -> safe to overwrite with X.
    __syncthreads();

    // --- Phase 2: DMA the 128x128 f32 X tile into the SAME 64 KB (16 x 1KB
    // bursts per wave). Linear LDS dest + pre-swizzled SOURCE column chunk:
    // LDS 16B-chunk (row, c16) holds global chunk (row, c16 ^ ((row&12)>>1)),
    // giving conflict-free quad-spread epilogue reads (verified in R4).
    const float* gX = X + (size_t)bi * VOCAB + bj;
#pragma unroll
    for (int t = 0; t < 16; ++t) {
        int g   = wave * 16 + t;          // 1-KB chunk id, wave-uniform
        int row = 2 * g + (lane >> 5);    // tile row 0..127 (per-lane)
        int c16 = lane & 31;              // 16B chunk within row
        int cs  = c16 ^ ((row & 12) >> 1);
        load_lds16(gX + (size_t)row * VOCAB + cs * 4, smX + g * 256);
    }
    asm volatile("s_waitcnt vmcnt(0)" ::: "memory");
    __builtin_amdgcn_s_barrier();

    // Epilogue. C/D layout: col(j) = lane&15, row(i) = quad*4 + reg.
    const int gj0 = bj + n_off;

    float tbv[4];
#pragma unroll
    for (int n = 0; n < 4; ++n) tbv[n] = tb[gj0 + n * 16 + ln];

    const float LN2 = 0.69314718055994531f;
    float sum = 0.0f;
#pragma unroll
    for (int m = 0; m < 4; ++m) {
#pragma unroll
        for (int r = 0; r < 4; ++r) {
            int il = m_off + m * 16 + quad * 4 + r;    // tile-local X row
            float cbi = cb[bi + il];
            const float* xrow = smX + il * 128;
#pragma unroll
            for (int n = 0; n < 4; ++n) {
                int col  = (n_off + n * 16) + ln;      // tile-local X col
                int c16s = (col >> 2) ^ (quad << 1);   // unswizzle 16B chunk
                float x  = xrow[(c16s << 2) + (col & 3)];
                float d  = acc[m][n][r] + tbv[n] + cbi - LN2 * hw_log2(1.0f + x);
                float xs = x * 0.01f;
                float w  = hw_exp2(0.75f * hw_log2(xs));   // xs^0.75; xs=0 -> 0
                w = fminf(w, 1.0f);
                sum = fmaf(w * d, d, sum);
            }
        }
    }

    // wave reduce -> cross-wave via LDS -> one plain store per block
#pragma unroll
    for (int off = 32; off > 0; off >>= 1) sum += __shfl_down(sum, off);

    __syncthreads();                       // all epilogue X reads done
    float* red = (float*)ldsbuf;
    if (lane == 0) red[wave] = sum;
    __syncthreads();
    if (tid == 0) {
        float v = red[0] + red[1] + red[2] + red[3];
        if (partial) partial[blockIdx.x] = v;   // no same-line contention
        else         atomicAdd(out, v);         // fallback if ws too small
    }
}

// Kernel 3: reduce the 9216 per-block partials (36KB, L2-hot) into out[0].
__global__ __launch_bounds__(256) void glove_reduce(
        const float* __restrict__ partial, float* __restrict__ out) {
    int tid = threadIdx.x;
    float s = 0.0f;
    const float4* p4 = (const float4*)partial;
    for (int k = tid; k < NBLK / 4; k += 256) {
        float4 v = p4[k];
        s += v.x + v.y + v.z + v.w;
    }
#pragma unroll
    for (int off = 32; off > 0; off >>= 1) s += __shfl_down(s, off);
    __shared__ float red[4];
    if ((tid & 63) == 0) red[tid >> 6] = s;
    __syncthreads();
    if (tid == 0) out[0] = red[0] + red[1] + red[2] + red[3];
}

extern "C" void kernel_launch(void* const* d_in, const int* in_sizes, int n_in,
                              void* d_out, int out_size, void* d_ws, size_t ws_size,
                              hipStream_t stream) {
    const float* X   = (const float*)d_in[0];
    const float* tgt = (const float*)d_in[1];
    const float* ctx = (const float*)d_in[2];
    const float* tb  = (const float*)d_in[3];
    const float* cb  = (const float*)d_in[4];
    float* out = (float*)d_out;

    u16* tgtb = (u16*)d_ws;
    u16* ctxb = tgtb + (size_t)VOCAB * EMB;

    // partial-sum array right after the two bf16 matrices (offset 6291456 B, 16B-aligned)
    const size_t emb_bytes = (size_t)VOCAB * EMB * sizeof(u16) * 2;
    float* partial = nullptr;
    if (ws_size >= emb_bytes + (size_t)NBLK * sizeof(float))
        partial = (float*)((char*)d_ws + emb_bytes);

    glove_prep<<<dim3(2 * (VOCAB * EMB / 4) / 256), 256, 0, stream>>>(
        tgt, ctx, tgtb, ctxb, out);
    glove_main<<<dim3(NBLK), 256, 0, stream>>>(
        X, ctxb, tgtb, tb, cb, out, partial);
    if (partial)
        glove_reduce<<<dim3(1), 256, 0, stream>>>(partial, out);
}